// Round 10
// baseline (69.641 us; speedup 1.0000x reference)
//
#include <hip/hip_runtime.h>
#include <math.h>

#define DD   64
#define WPB  4    // waves per 256-thread block, one batch row per wave
#define NLDS 32   // z elems broadcast via LDS+pk_fma; rest via readlane+fmac

typedef float v2f __attribute__((ext_vector_type(2)));

// Packed fp32 FMA (VOP3P): halves VALU count for the LDS-fed half.
__device__ __forceinline__ v2f pk_fma(v2f a, v2f b, v2f c) {
    v2f d;
    asm("v_pk_fma_f32 %0, %1, %2, %3" : "=v"(d) : "v"(a), "v"(b), "v"(c));
    return d;
}

// tanh(a) = 1 - 2/(e+1), e = exp2(a*2*log2(e)); 5 VALU instrs, no clamp
// needed (|zl| <= ~13 << 44 overflow).
__device__ __forceinline__ float fast_tanh(float a) {
    const float e = __builtin_amdgcn_exp2f(a * 2.885390081777927f);
    return fmaf(-2.0f, __builtin_amdgcn_rcpf(e + 1.0f), 1.0f);
}

__device__ __forceinline__ float rl(float v, int lane) {
    return __int_as_float(__builtin_amdgcn_readlane(__float_as_int(v), lane));
}

// zl = xi + dot(w,z), broadcast split to run BOTH pipes at parity:
//  z_0..31  -> 8 ds_read_b128 (~6.4cyc ea, LDS pipe)  + 16 v_pk_fma_f32
//  z_32..63 -> 32 v_readlane + 32 v_fmac (SGPR srcs, VALU pipe)
// Cost model from r7/r8/r9 residuals: LDS-side ~820 cyc/CU-iter, VALU-side
// ~800 cyc/CU-iter at 16 waves/CU -> concurrent, vs r9's all-LDS 1630.
__device__ __forceinline__ float matvec_split(const v2f* __restrict__ w2,
                                              const float* zs, float zv,
                                              float xi) {
    const float4* zs4 = reinterpret_cast<const float4*>(zs);
    v2f p0 = {xi, 0.0f}, p1 = {0.0f, 0.0f};
#pragma unroll
    for (int q = 0; q < NLDS / 4; q += 2) {      // 8 ds_read_b128
        const float4 u = zs4[q];
        const float4 v = zs4[q + 1];
        p0 = pk_fma(w2[2 * q],     (v2f){u.x, u.y}, p0);
        p1 = pk_fma(w2[2 * q + 1], (v2f){u.z, u.w}, p1);
        p0 = pk_fma(w2[2 * q + 2], (v2f){v.x, v.y}, p0);
        p1 = pk_fma(w2[2 * q + 3], (v2f){v.z, v.w}, p1);
    }
    const float* wf = reinterpret_cast<const float*>(w2);
    float a0 = 0.f, a1 = 0.f, a2 = 0.f, a3 = 0.f;
#pragma unroll
    for (int j = NLDS; j < DD; j += 4) {         // 32 readlane + 32 fmac
        a0 = fmaf(wf[j],     rl(zv, j),     a0);
        a1 = fmaf(wf[j + 1], rl(zv, j + 1), a1);
        a2 = fmaf(wf[j + 2], rl(zv, j + 2), a2);
        a3 = fmaf(wf[j + 3], rl(zv, j + 3), a3);
    }
    const v2f p = p0 + p1;
    return ((p.x + p.y) + (a0 + a1)) + (a2 + a3);
}

// One wave per batch row; lane i owns element i and W row i in registers.
// Single-wave lockstep: wave_barrier = compiler ordering fence only.
// Tol 8e-6: exit residual norm <= 8e-6*8 = 6.4e-5 < 1e-4 zeroing threshold
// (1.56x margin incl. ~5e-7 eval noise); saves ~2-3 iterations vs 2.5e-6.
__global__ __launch_bounds__(64 * WPB)
void tanh_fixed_point(const float* __restrict__ x,
                      const float* __restrict__ W,
                      float* __restrict__ out)
{
    __shared__ alignas(16) float zsh[WPB][NLDS];
    const int lane = threadIdx.x & 63;
    const int wid  = threadIdx.x >> 6;
    const int b    = blockIdx.x * WPB + wid;
    float* zs = zsh[wid];

    v2f w2[DD / 2];
#pragma unroll
    for (int j = 0; j < DD; j += 4) {
        const float4 v = *reinterpret_cast<const float4*>(W + lane * DD + j);
        w2[j / 2]     = (v2f){v.x, v.y};
        w2[j / 2 + 1] = (v2f){v.z, v.w};
    }

    const float xi = x[b * DD + lane];
    float z = fast_tanh(xi);            // z0 = tanh(x), as reference

    for (int it = 0; it < 64; ++it) {
        if (lane < NLDS) zs[lane] = z;
        __builtin_amdgcn_wave_barrier();
        const float zn = fast_tanh(matvec_split(w2, zs, z, xi));
        __builtin_amdgcn_wave_barrier();
        const bool conv = fabsf(zn - z) < 8e-6f;
        z = zn;
        if (__all(conv)) break;         // wave-uniform
    }

    // Mirror reference: zero rows with ||z - tanh(zW^T+x)||_2 > 1e-4.
    if (lane < NLDS) zs[lane] = z;
    __builtin_amdgcn_wave_barrier();
    const float g = z - fast_tanh(matvec_split(w2, zs, z, xi));
    float s = g * g;
#pragma unroll
    for (int off = 32; off; off >>= 1)
        s += __shfl_xor(s, off);
    if (s > 1e-8f) z = 0.0f;

    out[b * DD + lane] = z;
}

extern "C" void kernel_launch(void* const* d_in, const int* in_sizes, int n_in,
                              void* d_out, int out_size, void* d_ws, size_t ws_size,
                              hipStream_t stream)
{
    const float* x = (const float*)d_in[0];   // [B, 64] fp32
    const float* W = (const float*)d_in[1];   // [64, 64] fp32
    float* out     = (float*)d_out;           // [B, 64] fp32
    const int B = in_sizes[0] / DD;           // 4096
    tanh_fixed_point<<<B / WPB, 64 * WPB, 0, stream>>>(x, W, out);
}